// Round 1
// baseline (2685.488 us; speedup 1.0000x reference)
//
#include <hip/hip_runtime.h>
#include <hip/hip_bf16.h>
#include <math.h>

#define BATCH 4
#define DMODEL 256
#define LSEQ 4096
#define DINNER 512
#define NDBL 48

__device__ __forceinline__ float silu_f(float v) {
    return v / (1.0f + __expf(-v));
}

// ---------------------------------------------------------------------------
// style[b, e] = ada_b[e] + sum_c silu(time_emb[b,c]) * ada_w[e,c]
// ---------------------------------------------------------------------------
__global__ void style_kernel(const float* __restrict__ time_emb,
                             const float* __restrict__ ada_w,
                             const float* __restrict__ ada_b,
                             float* __restrict__ style) {
    int i = blockIdx.x * blockDim.x + threadIdx.x;  // 0..2047
    int b = i >> 9;
    int e = i & 511;
    const float* te = time_emb + b * DMODEL;
    const float* wr = ada_w + (size_t)e * DMODEL;
    float acc = ada_b[e];
    for (int c = 0; c < DMODEL; ++c)
        acc += silu_f(te[c]) * wr[c];
    style[i] = acc;
}

// ---------------------------------------------------------------------------
// LayerNorm over C + AdaLN modulation, with transpose (B,C,L) -> (B,L,C)
// one block = one b, 16 consecutive l values
// ---------------------------------------------------------------------------
__global__ __launch_bounds__(256) void ln_kernel(
    const float* __restrict__ x,      // (B, 256, 4096)
    const float* __restrict__ g,
    const float* __restrict__ bcoef,
    const float* __restrict__ style,  // (B, 512)
    float* __restrict__ xnorm)        // (B, 4096, 256)
{
    __shared__ float tile[DMODEL][17];
    __shared__ float psum[16][17], psq[16][17];
    __shared__ float mu_s[16], rs_s[16];
    int tid = threadIdx.x;
    int blk = blockIdx.x;            // B * 256 blocks
    int b = blk >> 8;
    int l0 = (blk & 255) * 16;
    const float* xb = x + (size_t)b * DMODEL * LSEQ;
    for (int r = 0; r < 16; ++r) {
        int idx = tid + r * 256;
        int c = idx >> 4, li = idx & 15;
        tile[c][li] = xb[(size_t)c * LSEQ + l0 + li];
    }
    __syncthreads();
    {
        int li = tid & 15, gq = tid >> 4;
        float s = 0.f, s2 = 0.f;
        for (int c = gq * 16; c < gq * 16 + 16; ++c) {
            float v = tile[c][li];
            s += v; s2 += v * v;
        }
        psum[li][gq] = s; psq[li][gq] = s2;
    }
    __syncthreads();
    if (tid < 16) {
        float s = 0.f, s2 = 0.f;
        for (int gq = 0; gq < 16; ++gq) { s += psum[tid][gq]; s2 += psq[tid][gq]; }
        float mu = s * (1.0f / 256.0f);
        float var = s2 * (1.0f / 256.0f) - mu * mu;
        mu_s[tid] = mu;
        rs_s[tid] = rsqrtf(var + 1e-5f);
    }
    __syncthreads();
    float gg = g[tid], bb = bcoef[tid];
    float sc = 1.0f + style[b * 512 + tid];
    float sh = style[b * 512 + 256 + tid];
    float* outb = xnorm + ((size_t)b * LSEQ + l0) * DMODEL;
    for (int li = 0; li < 16; ++li) {
        float v = tile[tid][li];
        float ynorm = (v - mu_s[li]) * rs_s[li] * gg + bb;
        outb[(size_t)li * DMODEL + tid] = ynorm * sc + sh;
    }
}

// ---------------------------------------------------------------------------
// Generic NT GEMM: C[m,n] = sum_k A[m,k] * W[n,k]
// M fixed = 16384 (B*L). Tiles 64x64x16, 256 threads, 4x4 per thread.
// MODE 0: write xi (n<512 -> C0) / z (n>=512 -> C1); A rows reversed if rev.
// MODE 1: write dbl (ld 48, guard n<48)
// MODE 2: accumulate into out_sum (ld 256), rows reversed on store if rev
// MODE 3: final proj: += bias, transpose-write out (B,C,L) with residual xres
// ---------------------------------------------------------------------------
template<int MODE>
__global__ __launch_bounds__(256) void gemm_nt(
    const float* __restrict__ A, const float* __restrict__ W,
    float* __restrict__ C0, float* __restrict__ C1,
    const float* __restrict__ bias, const float* __restrict__ xres,
    int N, int K, int rev)
{
    __shared__ float As[16][68];
    __shared__ float Ws[16][68];
    int tid = threadIdx.x;
    int tx = tid & 15, ty = tid >> 4;
    int bx = blockIdx.x, by = blockIdx.y;
    int lr = tid >> 2;          // 0..63 row within tile
    int kq = (tid & 3) * 4;

    int mrow = by * 64 + lr;
    int msrc = mrow;
    if (MODE == 0 && rev) {
        int b = mrow >> 12, l = mrow & 4095;
        msrc = (b << 12) | (4095 - l);
    }
    const float* Arow = A + (size_t)msrc * K + kq;
    int wn = bx * 64 + lr;
    bool wvalid = (wn < N);
    const float* Wrow = W + (size_t)(wvalid ? wn : 0) * K + kq;

    float acc[4][4];
    #pragma unroll
    for (int i = 0; i < 4; ++i)
        #pragma unroll
        for (int j = 0; j < 4; ++j) acc[i][j] = 0.f;

    for (int k0 = 0; k0 < K; k0 += 16) {
        float4 av = *reinterpret_cast<const float4*>(Arow + k0);
        float4 wv = wvalid ? *reinterpret_cast<const float4*>(Wrow + k0)
                           : make_float4(0.f, 0.f, 0.f, 0.f);
        __syncthreads();
        As[kq + 0][lr] = av.x; As[kq + 1][lr] = av.y;
        As[kq + 2][lr] = av.z; As[kq + 3][lr] = av.w;
        Ws[kq + 0][lr] = wv.x; Ws[kq + 1][lr] = wv.y;
        Ws[kq + 2][lr] = wv.z; Ws[kq + 3][lr] = wv.w;
        __syncthreads();
        #pragma unroll
        for (int kk = 0; kk < 16; ++kk) {
            float4 a4 = *reinterpret_cast<const float4*>(&As[kk][ty * 4]);
            float4 w4 = *reinterpret_cast<const float4*>(&Ws[kk][tx * 4]);
            float af[4] = {a4.x, a4.y, a4.z, a4.w};
            float wf[4] = {w4.x, w4.y, w4.z, w4.w};
            #pragma unroll
            for (int i = 0; i < 4; ++i)
                #pragma unroll
                for (int j = 0; j < 4; ++j)
                    acc[i][j] = fmaf(af[i], wf[j], acc[i][j]);
        }
    }

    int m = by * 64 + ty * 4;
    int n = bx * 64 + tx * 4;
    if (MODE == 0) {
        #pragma unroll
        for (int i = 0; i < 4; ++i) {
            float4 v = make_float4(acc[i][0], acc[i][1], acc[i][2], acc[i][3]);
            size_t row = (size_t)(m + i);
            if (n < 512)
                *reinterpret_cast<float4*>(C0 + row * 512 + n) = v;
            else
                *reinterpret_cast<float4*>(C1 + row * 512 + (n - 512)) = v;
        }
    } else if (MODE == 1) {
        if (n < NDBL) {
            #pragma unroll
            for (int i = 0; i < 4; ++i) {
                float4 v = make_float4(acc[i][0], acc[i][1], acc[i][2], acc[i][3]);
                *reinterpret_cast<float4*>(C0 + (size_t)(m + i) * NDBL + n) = v;
            }
        }
    } else if (MODE == 2) {
        #pragma unroll
        for (int i = 0; i < 4; ++i) {
            int mr = m + i;
            int mdst = mr;
            if (rev) { int b = mr >> 12, l = mr & 4095; mdst = (b << 12) | (4095 - l); }
            float4* p = reinterpret_cast<float4*>(C0 + (size_t)mdst * 256 + n);
            float4 old = *p;
            old.x += acc[i][0]; old.y += acc[i][1];
            old.z += acc[i][2]; old.w += acc[i][3];
            *p = old;
        }
    } else {
        __shared__ float Ct[64][65];
        #pragma unroll
        for (int i = 0; i < 4; ++i)
            #pragma unroll
            for (int j = 0; j < 4; ++j)
                Ct[tx * 4 + j][ty * 4 + i] = acc[i][j] + bias[n + j];
        __syncthreads();
        int b = (by * 64) >> 12;
        int l0 = (by * 64) & 4095;
        int c0 = bx * 64;
        const float* xr = xres + ((size_t)b * DMODEL + c0) * LSEQ + l0;
        float* outp = C0 + ((size_t)b * DMODEL + c0) * LSEQ + l0;
        for (int r = 0; r < 16; ++r) {
            int flat = tid + r * 256;
            int cl = flat >> 6, ll = flat & 63;
            outp[(size_t)cl * LSEQ + ll] = xr[(size_t)cl * LSEQ + ll] + Ct[cl][ll];
        }
    }
}

// ---------------------------------------------------------------------------
// depthwise causal conv (k=4) + bias + silu
// ---------------------------------------------------------------------------
__global__ void conv_kernel(const float* __restrict__ xi,
                            const float* __restrict__ convW,
                            const float* __restrict__ convB,
                            float* __restrict__ xc) {
    int gid = blockIdx.x * 256 + threadIdx.x;   // B*L*512 = 2^23
    int d = gid & 511;
    int t = (gid >> 9) & 4095;
    int b = gid >> 21;
    const float* w = convW + d * 4;
    float acc = convB[d];
    const float* base = xi + (((size_t)b << 12) + t) * 512 + d;
    #pragma unroll
    for (int k = 0; k < 4; ++k) {
        int tt = t - 3 + k;
        if (tt >= 0) acc += base[(size_t)(k - 3) * 512] * w[k];
    }
    xc[gid] = silu_f(acc);
}

// ---------------------------------------------------------------------------
// dt[row, d] = softplus( sum_r dbl[row, r] * dtW[d, r] + dtB[d] )
// ---------------------------------------------------------------------------
__global__ __launch_bounds__(512) void dt_kernel(
    const float* __restrict__ dbl, const float* __restrict__ dtW,
    const float* __restrict__ dtB, float* __restrict__ dt)
{
    __shared__ float dtr_s[16];
    int row = blockIdx.x;         // B*L
    int d = threadIdx.x;          // 512
    if (d < 16) dtr_s[d] = dbl[(size_t)row * NDBL + d];
    __syncthreads();
    const float* wr = dtW + d * 16;
    float acc = dtB[d];
    #pragma unroll
    for (int r = 0; r < 16; ++r) acc += dtr_s[r] * wr[r];
    float sp = (acc > 20.f) ? acc : log1pf(__expf(acc));
    dt[(size_t)row * 512 + d] = sp;
}

// ---------------------------------------------------------------------------
// selective scan. block = (b, 16 channels), thread = (d_local, n_state).
// y written in place over dt buffer. y = (scan + xc*D) * silu(z)
// ---------------------------------------------------------------------------
__global__ __launch_bounds__(256) void scan_kernel(
    const float* __restrict__ dt,
    float* __restrict__ y,            // same buffer as dt (in-place)
    const float* __restrict__ xc,
    const float* __restrict__ z,
    const float* __restrict__ dbl,
    const float* __restrict__ Alog,
    const float* __restrict__ Dp)
{
    __shared__ float dtT[64][16], xcT[64][16], zT[64][16],
                     BT[64][16], CT[64][16], yT[64][16];
    int tid = threadIdx.x;
    int b = blockIdx.x >> 5;
    int d0 = (blockIdx.x & 31) * 16;
    int dl = tid >> 4, n = tid & 15;
    int d = d0 + dl;
    float A_dn = -__expf(Alog[d * 16 + n]);
    float Dv = Dp[d];
    float h = 0.f;
    size_t basebt = (size_t)b * 4096;
    for (int t0 = 0; t0 < 4096; t0 += 64) {
        for (int r = 0; r < 4; ++r) {
            int idx = tid + r * 256;
            int i = idx >> 4, j = idx & 15;
            size_t row = basebt + t0 + i;
            dtT[i][j] = dt[row * 512 + d0 + j];
            xcT[i][j] = xc[row * 512 + d0 + j];
            zT[i][j]  = z [row * 512 + d0 + j];
            BT[i][j]  = dbl[row * 48 + 16 + j];
            CT[i][j]  = dbl[row * 48 + 32 + j];
        }
        __syncthreads();
        for (int i = 0; i < 64; ++i) {
            float sdt = dtT[i][dl];
            float sx  = xcT[i][dl];
            float dA = __expf(sdt * A_dn);
            h = fmaf(dA, h, sdt * sx * BT[i][n]);
            float p = h * CT[i][n];
            p += __shfl_xor(p, 1);
            p += __shfl_xor(p, 2);
            p += __shfl_xor(p, 4);
            p += __shfl_xor(p, 8);
            if (n == 0) {
                float zv = zT[i][dl];
                yT[i][dl] = (p + sx * Dv) * silu_f(zv);
            }
        }
        __syncthreads();
        for (int r = 0; r < 4; ++r) {
            int idx = tid + r * 256;
            int i = idx >> 4, j = idx & 15;
            size_t row = basebt + t0 + i;
            y[row * 512 + d0 + j] = yT[i][j];
        }
        __syncthreads();
    }
}

// ---------------------------------------------------------------------------
extern "C" void kernel_launch(void* const* d_in, const int* in_sizes, int n_in,
                              void* d_out, int out_size, void* d_ws, size_t ws_size,
                              hipStream_t stream) {
    const float* x        = (const float*)d_in[0];
    const float* time_emb = (const float*)d_in[1];
    const float* ln_g     = (const float*)d_in[2];
    const float* ln_b     = (const float*)d_in[3];
    const float* ada_w    = (const float*)d_in[4];
    const float* ada_b    = (const float*)d_in[5];
    const float* proj_w   = (const float*)d_in[6];
    const float* proj_b   = (const float*)d_in[7];

    float* ws = (float*)d_ws;
    float* style  = ws;                    // 4096
    float* xnorm  = style + 4096;          // 4,194,304
    float* bufA   = xnorm + 4194304;       // 8,388,608  (xi -> dt -> y)
    float* bufZ   = bufA + 8388608;        // 8,388,608
    float* bufXC  = bufZ + 8388608;        // 8,388,608
    float* bufDBL = bufXC + 8388608;       // 786,432
    float* outsum = bufDBL + 786432;       // 4,194,304
    float* outp   = (float*)d_out;

    hipMemsetAsync(outsum, 0, (size_t)4194304 * sizeof(float), stream);
    style_kernel<<<8, 256, 0, stream>>>(time_emb, ada_w, ada_b, style);
    ln_kernel<<<BATCH * 256, 256, 0, stream>>>(x, ln_g, ln_b, style, xnorm);

    for (int dir = 0; dir < 2; ++dir) {
        const float* inW    = (const float*)d_in[8 + dir * 9];
        const float* convW  = (const float*)d_in[9 + dir * 9];
        const float* convB  = (const float*)d_in[10 + dir * 9];
        const float* xprojW = (const float*)d_in[11 + dir * 9];
        const float* dtW    = (const float*)d_in[12 + dir * 9];
        const float* dtB    = (const float*)d_in[13 + dir * 9];
        const float* Alog   = (const float*)d_in[14 + dir * 9];
        const float* Dp     = (const float*)d_in[15 + dir * 9];
        const float* outW   = (const float*)d_in[16 + dir * 9];

        gemm_nt<0><<<dim3(16, 256), 256, 0, stream>>>(
            xnorm, inW, bufA, bufZ, nullptr, nullptr, 1024, 256, dir);
        conv_kernel<<<32768, 256, 0, stream>>>(bufA, convW, convB, bufXC);
        gemm_nt<1><<<dim3(1, 256), 256, 0, stream>>>(
            bufXC, xprojW, bufDBL, nullptr, nullptr, nullptr, 48, 512, 0);
        dt_kernel<<<16384, 512, 0, stream>>>(bufDBL, dtW, dtB, bufA);
        scan_kernel<<<128, 256, 0, stream>>>(
            bufA, bufA, bufXC, bufZ, bufDBL, Alog, Dp);
        gemm_nt<2><<<dim3(4, 256), 256, 0, stream>>>(
            bufA, outW, outsum, nullptr, nullptr, nullptr, 256, 512, dir);
    }
    gemm_nt<3><<<dim3(4, 256), 256, 0, stream>>>(
        outsum, proj_w, outp, nullptr, proj_b, x, 256, 256, 0);
}

// Round 2
// 830.222 us; speedup vs baseline: 3.2347x; 3.2347x over previous
//
#include <hip/hip_runtime.h>
#include <hip/hip_bf16.h>
#include <math.h>

#define BATCH 4
#define DMODEL 256
#define LSEQ 4096
#define DINNER 512
#define NDBL 48

__device__ __forceinline__ float silu_f(float v) {
    return v / (1.0f + __expf(-v));
}

// ---------------------------------------------------------------------------
// style[b, e] = ada_b[e] + sum_c silu(time_emb[b,c]) * ada_w[e,c]
// ---------------------------------------------------------------------------
__global__ void style_kernel(const float* __restrict__ time_emb,
                             const float* __restrict__ ada_w,
                             const float* __restrict__ ada_b,
                             float* __restrict__ style) {
    int i = blockIdx.x * blockDim.x + threadIdx.x;  // 0..2047
    int b = i >> 9;
    int e = i & 511;
    const float* te = time_emb + b * DMODEL;
    const float* wr = ada_w + (size_t)e * DMODEL;
    float acc = ada_b[e];
    for (int c = 0; c < DMODEL; ++c)
        acc += silu_f(te[c]) * wr[c];
    style[i] = acc;
}

// ---------------------------------------------------------------------------
// LayerNorm over C + AdaLN modulation, with transpose (B,C,L) -> (B,L,C)
// ---------------------------------------------------------------------------
__global__ __launch_bounds__(256) void ln_kernel(
    const float* __restrict__ x,      // (B, 256, 4096)
    const float* __restrict__ g,
    const float* __restrict__ bcoef,
    const float* __restrict__ style,  // (B, 512)
    float* __restrict__ xnorm)        // (B, 4096, 256)
{
    __shared__ float tile[DMODEL][17];
    __shared__ float psum[16][17], psq[16][17];
    __shared__ float mu_s[16], rs_s[16];
    int tid = threadIdx.x;
    int blk = blockIdx.x;            // B * 256 blocks
    int b = blk >> 8;
    int l0 = (blk & 255) * 16;
    const float* xb = x + (size_t)b * DMODEL * LSEQ;
    for (int r = 0; r < 16; ++r) {
        int idx = tid + r * 256;
        int c = idx >> 4, li = idx & 15;
        tile[c][li] = xb[(size_t)c * LSEQ + l0 + li];
    }
    __syncthreads();
    {
        int li = tid & 15, gq = tid >> 4;
        float s = 0.f, s2 = 0.f;
        for (int c = gq * 16; c < gq * 16 + 16; ++c) {
            float v = tile[c][li];
            s += v; s2 += v * v;
        }
        psum[li][gq] = s; psq[li][gq] = s2;
    }
    __syncthreads();
    if (tid < 16) {
        float s = 0.f, s2 = 0.f;
        for (int gq = 0; gq < 16; ++gq) { s += psum[tid][gq]; s2 += psq[tid][gq]; }
        float mu = s * (1.0f / 256.0f);
        float var = s2 * (1.0f / 256.0f) - mu * mu;
        mu_s[tid] = mu;
        rs_s[tid] = rsqrtf(var + 1e-5f);
    }
    __syncthreads();
    float gg = g[tid], bb = bcoef[tid];
    float sc = 1.0f + style[b * 512 + tid];
    float sh = style[b * 512 + 256 + tid];
    float* outb = xnorm + ((size_t)b * LSEQ + l0) * DMODEL;
    for (int li = 0; li < 16; ++li) {
        float v = tile[tid][li];
        float ynorm = (v - mu_s[li]) * rs_s[li] * gg + bb;
        outb[(size_t)li * DMODEL + tid] = ynorm * sc + sh;
    }
}

// ---------------------------------------------------------------------------
// Generic NT GEMM: C[m,n] = sum_k A[m,k] * W[n,k]
// ---------------------------------------------------------------------------
template<int MODE>
__global__ __launch_bounds__(256) void gemm_nt(
    const float* __restrict__ A, const float* __restrict__ W,
    float* __restrict__ C0, float* __restrict__ C1,
    const float* __restrict__ bias, const float* __restrict__ xres,
    int N, int K, int rev)
{
    __shared__ float As[16][68];
    __shared__ float Ws[16][68];
    int tid = threadIdx.x;
    int tx = tid & 15, ty = tid >> 4;
    int bx = blockIdx.x, by = blockIdx.y;
    int lr = tid >> 2;          // 0..63 row within tile
    int kq = (tid & 3) * 4;

    int mrow = by * 64 + lr;
    int msrc = mrow;
    if (MODE == 0 && rev) {
        int b = mrow >> 12, l = mrow & 4095;
        msrc = (b << 12) | (4095 - l);
    }
    const float* Arow = A + (size_t)msrc * K + kq;
    int wn = bx * 64 + lr;
    bool wvalid = (wn < N);
    const float* Wrow = W + (size_t)(wvalid ? wn : 0) * K + kq;

    float acc[4][4];
    #pragma unroll
    for (int i = 0; i < 4; ++i)
        #pragma unroll
        for (int j = 0; j < 4; ++j) acc[i][j] = 0.f;

    for (int k0 = 0; k0 < K; k0 += 16) {
        float4 av = *reinterpret_cast<const float4*>(Arow + k0);
        float4 wv = wvalid ? *reinterpret_cast<const float4*>(Wrow + k0)
                           : make_float4(0.f, 0.f, 0.f, 0.f);
        __syncthreads();
        As[kq + 0][lr] = av.x; As[kq + 1][lr] = av.y;
        As[kq + 2][lr] = av.z; As[kq + 3][lr] = av.w;
        Ws[kq + 0][lr] = wv.x; Ws[kq + 1][lr] = wv.y;
        Ws[kq + 2][lr] = wv.z; Ws[kq + 3][lr] = wv.w;
        __syncthreads();
        #pragma unroll
        for (int kk = 0; kk < 16; ++kk) {
            float4 a4 = *reinterpret_cast<const float4*>(&As[kk][ty * 4]);
            float4 w4 = *reinterpret_cast<const float4*>(&Ws[kk][tx * 4]);
            float af[4] = {a4.x, a4.y, a4.z, a4.w};
            float wf[4] = {w4.x, w4.y, w4.z, w4.w};
            #pragma unroll
            for (int i = 0; i < 4; ++i)
                #pragma unroll
                for (int j = 0; j < 4; ++j)
                    acc[i][j] = fmaf(af[i], wf[j], acc[i][j]);
        }
    }

    int m = by * 64 + ty * 4;
    int n = bx * 64 + tx * 4;
    if (MODE == 0) {
        #pragma unroll
        for (int i = 0; i < 4; ++i) {
            float4 v = make_float4(acc[i][0], acc[i][1], acc[i][2], acc[i][3]);
            size_t row = (size_t)(m + i);
            if (n < 512)
                *reinterpret_cast<float4*>(C0 + row * 512 + n) = v;
            else
                *reinterpret_cast<float4*>(C1 + row * 512 + (n - 512)) = v;
        }
    } else if (MODE == 1) {
        if (n < NDBL) {
            #pragma unroll
            for (int i = 0; i < 4; ++i) {
                float4 v = make_float4(acc[i][0], acc[i][1], acc[i][2], acc[i][3]);
                *reinterpret_cast<float4*>(C0 + (size_t)(m + i) * NDBL + n) = v;
            }
        }
    } else if (MODE == 2) {
        #pragma unroll
        for (int i = 0; i < 4; ++i) {
            int mr = m + i;
            int mdst = mr;
            if (rev) { int b = mr >> 12, l = mr & 4095; mdst = (b << 12) | (4095 - l); }
            float4* p = reinterpret_cast<float4*>(C0 + (size_t)mdst * 256 + n);
            float4 old = *p;
            old.x += acc[i][0]; old.y += acc[i][1];
            old.z += acc[i][2]; old.w += acc[i][3];
            *p = old;
        }
    } else {
        __shared__ float Ct[64][65];
        #pragma unroll
        for (int i = 0; i < 4; ++i)
            #pragma unroll
            for (int j = 0; j < 4; ++j)
                Ct[tx * 4 + j][ty * 4 + i] = acc[i][j] + bias[n + j];
        __syncthreads();
        int b = (by * 64) >> 12;
        int l0 = (by * 64) & 4095;
        int c0 = bx * 64;
        const float* xr = xres + ((size_t)b * DMODEL + c0) * LSEQ + l0;
        float* outp = C0 + ((size_t)b * DMODEL + c0) * LSEQ + l0;
        for (int r = 0; r < 16; ++r) {
            int flat = tid + r * 256;
            int cl = flat >> 6, ll = flat & 63;
            outp[(size_t)cl * LSEQ + ll] = xr[(size_t)cl * LSEQ + ll] + Ct[cl][ll];
        }
    }
}

// ---------------------------------------------------------------------------
// depthwise causal conv (k=4) + bias + silu
// ---------------------------------------------------------------------------
__global__ void conv_kernel(const float* __restrict__ xi,
                            const float* __restrict__ convW,
                            const float* __restrict__ convB,
                            float* __restrict__ xc) {
    int gid = blockIdx.x * 256 + threadIdx.x;   // B*L*512 = 2^23
    int d = gid & 511;
    int t = (gid >> 9) & 4095;
    int b = gid >> 21;
    const float* w = convW + d * 4;
    float acc = convB[d];
    const float* base = xi + (((size_t)b << 12) + t) * 512 + d;
    #pragma unroll
    for (int k = 0; k < 4; ++k) {
        int tt = t - 3 + k;
        if (tt >= 0) acc += base[(size_t)(k - 3) * 512] * w[k];
    }
    xc[gid] = silu_f(acc);
}

// ---------------------------------------------------------------------------
// dt[row, d] = softplus( sum_r dbl[row, r] * dtW[d, r] + dtB[d] )
// ---------------------------------------------------------------------------
__global__ __launch_bounds__(512) void dt_kernel(
    const float* __restrict__ dbl, const float* __restrict__ dtW,
    const float* __restrict__ dtB, float* __restrict__ dt)
{
    __shared__ float dtr_s[16];
    int row = blockIdx.x;         // B*L
    int d = threadIdx.x;          // 512
    if (d < 16) dtr_s[d] = dbl[(size_t)row * NDBL + d];
    __syncthreads();
    const float* wr = dtW + d * 16;
    float acc = dtB[d];
    #pragma unroll
    for (int r = 0; r < 16; ++r) acc += dtr_s[r] * wr[r];
    float sp = (acc > 20.f) ? acc : log1pf(__expf(acc));
    dt[(size_t)row * 512 + d] = sp;
}

// ===========================================================================
// Chunked selective scan. L=4096 split into 64 chunks of 64 steps.
// Thread = one (b, d); all 16 states in registers (no cross-lane ops).
// Phase A: per-chunk decay product P[n] and local scan end H[n] (h0 = 0).
// Phase B: inter-chunk scan over the 64 chunks per (b,d,n) -> h_start.
// Phase C: replay chunk with true h_start, emit y = (h.C + x*D) * silu(z).
// Chunk-state layout: [c][b][d][n] -> ((c*4+b)*512+d)*16+n (coalesced both ways)
// ===========================================================================
#define NCHUNK 64
#define CLEN 64

__global__ __launch_bounds__(256) void scanA_kernel(
    const float* __restrict__ dt,
    const float* __restrict__ xc,
    const float* __restrict__ dbl,
    const float* __restrict__ Alog,
    float* __restrict__ chunkP,
    float* __restrict__ chunkH)
{
    __shared__ float B_s[CLEN][16];
    int tid = threadIdx.x;
    int d = blockIdx.x * 256 + tid;
    int c = blockIdx.y;
    int b = blockIdx.z;
    int t0 = c * CLEN;
    size_t baserow = (size_t)b * LSEQ + t0;
    #pragma unroll
    for (int r = 0; r < 4; ++r) {
        int idx = tid + r * 256;
        int i = idx >> 4, n = idx & 15;
        B_s[i][n] = dbl[(baserow + i) * NDBL + 16 + n];
    }
    __syncthreads();
    float A[16];
    #pragma unroll
    for (int q = 0; q < 4; ++q) {
        float4 al = *reinterpret_cast<const float4*>(Alog + d * 16 + q * 4);
        A[q * 4 + 0] = -__expf(al.x); A[q * 4 + 1] = -__expf(al.y);
        A[q * 4 + 2] = -__expf(al.z); A[q * 4 + 3] = -__expf(al.w);
    }
    float h[16], P[16];
    #pragma unroll
    for (int n = 0; n < 16; ++n) { h[n] = 0.f; P[n] = 1.f; }
    #pragma unroll 2
    for (int i = 0; i < CLEN; ++i) {
        float sdt = dt[(baserow + i) * 512 + d];
        float sx  = xc[(baserow + i) * 512 + d];
        float u = sdt * sx;
        #pragma unroll
        for (int n = 0; n < 16; ++n) {
            float dA = __expf(sdt * A[n]);
            h[n] = fmaf(dA, h[n], u * B_s[i][n]);
            P[n] *= dA;
        }
    }
    size_t o = (((size_t)c * 4 + b) * 512 + d) * 16;
    #pragma unroll
    for (int q = 0; q < 4; ++q) {
        *reinterpret_cast<float4*>(chunkP + o + q * 4) =
            make_float4(P[q*4], P[q*4+1], P[q*4+2], P[q*4+3]);
        *reinterpret_cast<float4*>(chunkH + o + q * 4) =
            make_float4(h[q*4], h[q*4+1], h[q*4+2], h[q*4+3]);
    }
}

__global__ __launch_bounds__(256) void scanB_kernel(
    const float* __restrict__ chunkP,
    float* __restrict__ chunkH)      // in-place: H -> h_start
{
    int idx = blockIdx.x * 256 + threadIdx.x;   // (b*512+d)*16+n, 32768 total
    float h = 0.f;
    for (int c = 0; c < NCHUNK; ++c) {
        size_t o = (size_t)c * 32768 + idx;
        float Pv = chunkP[o];
        float Hv = chunkH[o];
        chunkH[o] = h;
        h = fmaf(Pv, h, Hv);
    }
}

__global__ __launch_bounds__(256) void scanC_kernel(
    const float* __restrict__ dt,
    float* __restrict__ y,            // in-place over dt
    const float* __restrict__ xc,
    const float* __restrict__ z,
    const float* __restrict__ dbl,
    const float* __restrict__ Alog,
    const float* __restrict__ Dp,
    const float* __restrict__ chunkH) // h_start
{
    __shared__ float B_s[CLEN][16];
    __shared__ float C_s[CLEN][16];
    int tid = threadIdx.x;
    int d = blockIdx.x * 256 + tid;
    int c = blockIdx.y;
    int b = blockIdx.z;
    int t0 = c * CLEN;
    size_t baserow = (size_t)b * LSEQ + t0;
    #pragma unroll
    for (int r = 0; r < 4; ++r) {
        int idx = tid + r * 256;
        int i = idx >> 4, n = idx & 15;
        B_s[i][n] = dbl[(baserow + i) * NDBL + 16 + n];
        C_s[i][n] = dbl[(baserow + i) * NDBL + 32 + n];
    }
    __syncthreads();
    float A[16];
    #pragma unroll
    for (int q = 0; q < 4; ++q) {
        float4 al = *reinterpret_cast<const float4*>(Alog + d * 16 + q * 4);
        A[q * 4 + 0] = -__expf(al.x); A[q * 4 + 1] = -__expf(al.y);
        A[q * 4 + 2] = -__expf(al.z); A[q * 4 + 3] = -__expf(al.w);
    }
    float Dv = Dp[d];
    float h[16];
    size_t o = (((size_t)c * 4 + b) * 512 + d) * 16;
    #pragma unroll
    for (int q = 0; q < 4; ++q) {
        float4 hv = *reinterpret_cast<const float4*>(chunkH + o + q * 4);
        h[q*4] = hv.x; h[q*4+1] = hv.y; h[q*4+2] = hv.z; h[q*4+3] = hv.w;
    }
    #pragma unroll 2
    for (int i = 0; i < CLEN; ++i) {
        size_t row = baserow + i;
        float sdt = dt[row * 512 + d];
        float sx  = xc[row * 512 + d];
        float zv  = z [row * 512 + d];
        float u = sdt * sx;
        float yacc = 0.f;
        #pragma unroll
        for (int n = 0; n < 16; ++n) {
            float dA = __expf(sdt * A[n]);
            h[n] = fmaf(dA, h[n], u * B_s[i][n]);
            yacc = fmaf(h[n], C_s[i][n], yacc);
        }
        y[row * 512 + d] = (yacc + sx * Dv) * silu_f(zv);
    }
}

// ---------------------------------------------------------------------------
extern "C" void kernel_launch(void* const* d_in, const int* in_sizes, int n_in,
                              void* d_out, int out_size, void* d_ws, size_t ws_size,
                              hipStream_t stream) {
    const float* x        = (const float*)d_in[0];
    const float* time_emb = (const float*)d_in[1];
    const float* ln_g     = (const float*)d_in[2];
    const float* ln_b     = (const float*)d_in[3];
    const float* ada_w    = (const float*)d_in[4];
    const float* ada_b    = (const float*)d_in[5];
    const float* proj_w   = (const float*)d_in[6];
    const float* proj_b   = (const float*)d_in[7];

    float* ws = (float*)d_ws;
    float* style  = ws;                    // 4096
    float* xnorm  = style + 4096;          // 4,194,304
    float* bufA   = xnorm + 4194304;       // 8,388,608  (xi -> dt -> y)
    float* bufZ   = bufA + 8388608;        // 8,388,608
    float* bufXC  = bufZ + 8388608;        // 8,388,608
    float* bufDBL = bufXC + 8388608;       // 786,432
    float* outsum = bufDBL + 786432;       // 4,194,304
    float* outp   = (float*)d_out;

    style_kernel<<<8, 256, 0, stream>>>(time_emb, ada_w, ada_b, style);
    ln_kernel<<<BATCH * 256, 256, 0, stream>>>(x, ln_g, ln_b, style, xnorm);

    for (int dir = 0; dir < 2; ++dir) {
        const float* inW    = (const float*)d_in[8 + dir * 9];
        const float* convW  = (const float*)d_in[9 + dir * 9];
        const float* convB  = (const float*)d_in[10 + dir * 9];
        const float* xprojW = (const float*)d_in[11 + dir * 9];
        const float* dtW    = (const float*)d_in[12 + dir * 9];
        const float* dtB    = (const float*)d_in[13 + dir * 9];
        const float* Alog   = (const float*)d_in[14 + dir * 9];
        const float* Dp     = (const float*)d_in[15 + dir * 9];
        const float* outW   = (const float*)d_in[16 + dir * 9];

        // chunk-state scratch (2 x 2,097,152 floats) aliases a dead buffer:
        // dir0 -> outsum (memset deferred until after scan), dir1 -> xnorm
        // (dead once dir1's in-proj GEMM below has consumed it).
        float* chunkP = (dir == 0) ? outsum : xnorm;
        float* chunkH = chunkP + 2097152;

        gemm_nt<0><<<dim3(16, 256), 256, 0, stream>>>(
            xnorm, inW, bufA, bufZ, nullptr, nullptr, 1024, 256, dir);
        conv_kernel<<<32768, 256, 0, stream>>>(bufA, convW, convB, bufXC);
        gemm_nt<1><<<dim3(1, 256), 256, 0, stream>>>(
            bufXC, xprojW, bufDBL, nullptr, nullptr, nullptr, 48, 512, 0);
        dt_kernel<<<16384, 512, 0, stream>>>(bufDBL, dtW, dtB, bufA);

        scanA_kernel<<<dim3(2, NCHUNK, BATCH), 256, 0, stream>>>(
            bufA, bufXC, bufDBL, Alog, chunkP, chunkH);
        scanB_kernel<<<128, 256, 0, stream>>>(chunkP, chunkH);
        scanC_kernel<<<dim3(2, NCHUNK, BATCH), 256, 0, stream>>>(
            bufA, bufA, bufXC, bufZ, bufDBL, Alog, Dp, chunkH);

        if (dir == 0)
            hipMemsetAsync(outsum, 0, (size_t)4194304 * sizeof(float), stream);
        gemm_nt<2><<<dim3(4, 256), 256, 0, stream>>>(
            bufA, outW, outsum, nullptr, nullptr, nullptr, 256, 512, dir);
    }
    gemm_nt<3><<<dim3(4, 256), 256, 0, stream>>>(
        outsum, proj_w, outp, nullptr, proj_b, x, 256, 256, 0);
}

// Round 3
// 439.824 us; speedup vs baseline: 6.1058x; 1.8876x over previous
//
#include <hip/hip_runtime.h>
#include <math.h>

#define BATCH 4
#define DMODEL 256
#define LSEQ 4096
#define DINNER 512
#define NDBL 48
#define NCHUNK 64
#define CLEN 64

typedef __attribute__((ext_vector_type(8))) short bfx8;
typedef __attribute__((ext_vector_type(4))) float f32x4;
typedef __attribute__((ext_vector_type(4))) unsigned short us4;

__device__ __forceinline__ float silu_f(float v) {
    return v / (1.0f + __expf(-v));
}
__device__ __forceinline__ unsigned short f2bf(float f) {
    union { float f; unsigned u; } v; v.f = f;
    unsigned r = v.u + 0x7fffu + ((v.u >> 16) & 1u);
    return (unsigned short)(r >> 16);
}
__device__ __forceinline__ float bf2f(unsigned short h) {
    union { unsigned u; float f; } v; v.u = ((unsigned)h) << 16;
    return v.f;
}

typedef __attribute__((address_space(1))) const unsigned int gas_u32;
typedef __attribute__((address_space(3))) unsigned int las_u32;
__device__ __forceinline__ void gload16(void* lds, const void* g) {
    __builtin_amdgcn_global_load_lds((gas_u32*)g, (las_u32*)lds, 16, 0, 0);
}

// ---------------------------------------------------------------------------
// style[b, e] = ada_b[e] + sum_c silu(time_emb[b,c]) * ada_w[e,c]
// ---------------------------------------------------------------------------
__global__ void style_kernel(const float* __restrict__ time_emb,
                             const float* __restrict__ ada_w,
                             const float* __restrict__ ada_b,
                             float* __restrict__ style) {
    int i = blockIdx.x * blockDim.x + threadIdx.x;  // 0..2047
    int b = i >> 9;
    int e = i & 511;
    const float* te = time_emb + b * DMODEL;
    const float* wr = ada_w + (size_t)e * DMODEL;
    float acc = ada_b[e];
    for (int c = 0; c < DMODEL; ++c)
        acc += silu_f(te[c]) * wr[c];
    style[i] = acc;
}

// ---------------------------------------------------------------------------
// LayerNorm over C + AdaLN, transpose (B,C,L) -> (B,L,C), bf16 out
// ---------------------------------------------------------------------------
__global__ __launch_bounds__(256) void ln_kernel(
    const float* __restrict__ x,
    const float* __restrict__ g,
    const float* __restrict__ bcoef,
    const float* __restrict__ style,
    unsigned short* __restrict__ xnorm)   // (B, 4096, 256) bf16
{
    __shared__ float tile[DMODEL][17];
    __shared__ float psum[16][17], psq[16][17];
    __shared__ float mu_s[16], rs_s[16];
    int tid = threadIdx.x;
    int blk = blockIdx.x;            // B * 256 blocks
    int b = blk >> 8;
    int l0 = (blk & 255) * 16;
    const float* xb = x + (size_t)b * DMODEL * LSEQ;
    for (int r = 0; r < 16; ++r) {
        int idx = tid + r * 256;
        int c = idx >> 4, li = idx & 15;
        tile[c][li] = xb[(size_t)c * LSEQ + l0 + li];
    }
    __syncthreads();
    {
        int li = tid & 15, gq = tid >> 4;
        float s = 0.f, s2 = 0.f;
        for (int c = gq * 16; c < gq * 16 + 16; ++c) {
            float v = tile[c][li];
            s += v; s2 += v * v;
        }
        psum[li][gq] = s; psq[li][gq] = s2;
    }
    __syncthreads();
    if (tid < 16) {
        float s = 0.f, s2 = 0.f;
        for (int gq = 0; gq < 16; ++gq) { s += psum[tid][gq]; s2 += psq[tid][gq]; }
        float mu = s * (1.0f / 256.0f);
        float var = s2 * (1.0f / 256.0f) - mu * mu;
        mu_s[tid] = mu;
        rs_s[tid] = rsqrtf(var + 1e-5f);
    }
    __syncthreads();
    float gg = g[tid], bb = bcoef[tid];
    float sc = 1.0f + style[b * 512 + tid];
    float sh = style[b * 512 + 256 + tid];
    unsigned short* outb = xnorm + ((size_t)b * LSEQ + l0) * DMODEL;
    for (int li = 0; li < 16; ++li) {
        float v = tile[tid][li];
        float ynorm = (v - mu_s[li]) * rs_s[li] * gg + bb;
        outb[(size_t)li * DMODEL + tid] = f2bf(ynorm * sc + sh);
    }
}

// ---------------------------------------------------------------------------
// weight converters
// ---------------------------------------------------------------------------
__global__ void cvt_kernel(const float* __restrict__ src,
                           unsigned short* __restrict__ dst, int n) {
    int i = blockIdx.x * 256 + threadIdx.x;
    if (i < n) dst[i] = f2bf(src[i]);
}
// xprojW (48 x 512) -> 128 x 512 zero-padded
__global__ void cvt_pad48_kernel(const float* __restrict__ src,
                                 unsigned short* __restrict__ dst) {
    int i = blockIdx.x * 256 + threadIdx.x;   // 65536
    int r = i >> 9;
    dst[i] = (r < 48) ? f2bf(src[i]) : (unsigned short)0;
}
// Wcat (256 x 1024) = [f_outW | b_outW]
__global__ void cvt_cat_kernel(const float* __restrict__ s0,
                               const float* __restrict__ s1,
                               unsigned short* __restrict__ dst) {
    int i = blockIdx.x * 256 + threadIdx.x;   // 262144
    int n = i >> 10, k = i & 1023;
    float v = (k < 512) ? s0[n * 512 + k] : s1[n * 512 + (k - 512)];
    dst[i] = f2bf(v);
}

// ---------------------------------------------------------------------------
// bf16 MFMA GEMM: C[m,n] = sum_k A[m,k] * W[n,k]
// 128x128 tile, BK=64, 256 threads (4 waves, 2x2), 16x16x32 MFMA, m97-style
// MODE 0: in-proj  N=1024 K=256 : n<512 -> xi bf16, else z bf16; rev reads A
// MODE 1: x-proj   N=128p K=512 : store dbl f32 if n<48
// MODE 2: out-proj N=256  K=1024: store outsum bf16
// MODE 3: final    N=256  K=256 : store f32 + bias
// ---------------------------------------------------------------------------
template<int MODE>
__global__ __launch_bounds__(256) void mfma_gemm(
    const unsigned short* __restrict__ A,
    const unsigned short* __restrict__ W,
    void* __restrict__ out0, void* __restrict__ out1,
    const float* __restrict__ bias,
    int K, int rev)
{
    __shared__ short As[128 * 64];
    __shared__ short Bs[128 * 64];
    int tid = threadIdx.x;
    int lane = tid & 63;
    int wave = tid >> 6;
    int wm = wave >> 1, wn = wave & 1;
    int bx = blockIdx.x, by = blockIdx.y;

    f32x4 acc[4][4] = {};

    int rt = tid >> 3;            // 0..31
    int col = (tid & 7) * 8;
    int lr = lane & 15;
    int lk = (lane >> 4) * 8;

    for (int k0 = 0; k0 < K; k0 += 64) {
        __syncthreads();
        #pragma unroll
        for (int i = 0; i < 4; ++i) {
            int m = by * 128 + i * 32 + rt;
            int msrc = m;
            if (MODE == 0 && rev) msrc = (m & ~4095) | (4095 - (m & 4095));
            gload16(&As[i * 2048 + tid * 8], A + (size_t)msrc * K + k0 + col);
            int wrow = bx * 128 + i * 32 + rt;
            gload16(&Bs[i * 2048 + tid * 8], W + (size_t)wrow * K + k0 + col);
        }
        __syncthreads();
        #pragma unroll
        for (int kk = 0; kk < 2; ++kk) {
            bfx8 af[4], bf[4];
            #pragma unroll
            for (int mi = 0; mi < 4; ++mi)
                af[mi] = *reinterpret_cast<const bfx8*>(
                    &As[(wm * 64 + mi * 16 + lr) * 64 + kk * 32 + lk]);
            #pragma unroll
            for (int ni = 0; ni < 4; ++ni)
                bf[ni] = *reinterpret_cast<const bfx8*>(
                    &Bs[(wn * 64 + ni * 16 + lr) * 64 + kk * 32 + lk]);
            #pragma unroll
            for (int mi = 0; mi < 4; ++mi)
                #pragma unroll
                for (int ni = 0; ni < 4; ++ni)
                    acc[mi][ni] = __builtin_amdgcn_mfma_f32_16x16x32_bf16(
                        af[mi], bf[ni], acc[mi][ni], 0, 0, 0);
        }
    }

    int r0 = (lane >> 4) * 4;
    int c0l = lane & 15;
    #pragma unroll
    for (int mi = 0; mi < 4; ++mi) {
        #pragma unroll
        for (int ni = 0; ni < 4; ++ni) {
            int n = bx * 128 + wn * 64 + ni * 16 + c0l;
            #pragma unroll
            for (int r = 0; r < 4; ++r) {
                int m = by * 128 + wm * 64 + mi * 16 + r0 + r;
                float v = acc[mi][ni][r];
                if (MODE == 0) {
                    if (n < 512)
                        ((unsigned short*)out0)[(size_t)m * 512 + n] = f2bf(v);
                    else
                        ((unsigned short*)out1)[(size_t)m * 512 + n - 512] = f2bf(v);
                } else if (MODE == 1) {
                    if (n < NDBL) ((float*)out0)[(size_t)m * NDBL + n] = v;
                } else if (MODE == 2) {
                    ((unsigned short*)out0)[(size_t)m * 256 + n] = f2bf(v);
                } else {
                    ((float*)out0)[(size_t)m * 256 + n] = v + bias[n];
                }
            }
        }
    }
}

// ---------------------------------------------------------------------------
// depthwise causal conv (k=4) + bias + silu, bf16 in/out, 4 channels/thread
// ---------------------------------------------------------------------------
__global__ __launch_bounds__(256) void conv_kernel(
    const unsigned short* __restrict__ xi,
    const float* __restrict__ convW,
    const float* __restrict__ convB,
    unsigned short* __restrict__ xc)
{
    int gid = blockIdx.x * 256 + threadIdx.x;   // B*L*128
    int dq = gid & 127;
    int t  = (gid >> 7) & 4095;
    int b  = gid >> 19;
    int d0 = dq * 4;
    float acc[4];
    f32x4 wv[4];
    #pragma unroll
    for (int j = 0; j < 4; ++j) {
        acc[j] = convB[d0 + j];
        wv[j] = *reinterpret_cast<const f32x4*>(convW + (d0 + j) * 4);
    }
    size_t rowbase = (((size_t)b << 12) + t) * 512 + d0;
    #pragma unroll
    for (int k = 0; k < 4; ++k) {
        int tt = t - 3 + k;
        if (tt >= 0) {
            us4 v = *reinterpret_cast<const us4*>(xi + rowbase + (ptrdiff_t)(k - 3) * 512);
            #pragma unroll
            for (int j = 0; j < 4; ++j)
                acc[j] = fmaf(bf2f(v[j]), wv[j][k], acc[j]);
        }
    }
    us4 o;
    #pragma unroll
    for (int j = 0; j < 4; ++j) o[j] = f2bf(silu_f(acc[j]));
    *reinterpret_cast<us4*>(xc + rowbase) = o;
}

// ---------------------------------------------------------------------------
// dt[row, d] = softplus( sum_r dbl[row, r] * dtW[d, r] + dtB[d] ), bf16 out
// ---------------------------------------------------------------------------
__global__ __launch_bounds__(512) void dt_kernel(
    const float* __restrict__ dbl, const float* __restrict__ dtW,
    const float* __restrict__ dtB, unsigned short* __restrict__ dt)
{
    __shared__ float dtr_s[16];
    int row = blockIdx.x;
    int d = threadIdx.x;
    if (d < 16) dtr_s[d] = dbl[(size_t)row * NDBL + d];
    __syncthreads();
    const float* wr = dtW + d * 16;
    float acc = dtB[d];
    #pragma unroll
    for (int r = 0; r < 16; ++r) acc += dtr_s[r] * wr[r];
    float sp = (acc > 20.f) ? acc : log1pf(__expf(acc));
    dt[(size_t)row * 512 + d] = f2bf(sp);
}

// ===========================================================================
// Chunked selective scan (bf16 activations, fp32 state)
// ===========================================================================
__global__ __launch_bounds__(256) void scanA_kernel(
    const unsigned short* __restrict__ dt,
    const unsigned short* __restrict__ xc,
    const float* __restrict__ dbl,
    const float* __restrict__ Alog,
    float* __restrict__ chunkP,
    float* __restrict__ chunkH)
{
    __shared__ float B_s[CLEN][16];
    int tid = threadIdx.x;
    int d = blockIdx.x * 256 + tid;
    int c = blockIdx.y;
    int b = blockIdx.z;
    size_t baserow = (size_t)b * LSEQ + c * CLEN;
    #pragma unroll
    for (int r = 0; r < 4; ++r) {
        int idx = tid + r * 256;
        int i = idx >> 4, n = idx & 15;
        B_s[i][n] = dbl[(baserow + i) * NDBL + 16 + n];
    }
    __syncthreads();
    float A[16];
    #pragma unroll
    for (int q = 0; q < 4; ++q) {
        f32x4 al = *reinterpret_cast<const f32x4*>(Alog + d * 16 + q * 4);
        #pragma unroll
        for (int j = 0; j < 4; ++j) A[q * 4 + j] = -__expf(al[j]);
    }
    float h[16], P[16];
    #pragma unroll
    for (int n = 0; n < 16; ++n) { h[n] = 0.f; P[n] = 1.f; }
    #pragma unroll 2
    for (int i = 0; i < CLEN; ++i) {
        float sdt = bf2f(dt[(baserow + i) * 512 + d]);
        float sx  = bf2f(xc[(baserow + i) * 512 + d]);
        float u = sdt * sx;
        #pragma unroll
        for (int n = 0; n < 16; ++n) {
            float dA = __expf(sdt * A[n]);
            h[n] = fmaf(dA, h[n], u * B_s[i][n]);
            P[n] *= dA;
        }
    }
    size_t o = (((size_t)c * 4 + b) * 512 + d) * 16;
    #pragma unroll
    for (int q = 0; q < 4; ++q) {
        *reinterpret_cast<f32x4*>(chunkP + o + q * 4) =
            (f32x4){P[q*4], P[q*4+1], P[q*4+2], P[q*4+3]};
        *reinterpret_cast<f32x4*>(chunkH + o + q * 4) =
            (f32x4){h[q*4], h[q*4+1], h[q*4+2], h[q*4+3]};
    }
}

__global__ __launch_bounds__(256) void scanB_kernel(
    const float* __restrict__ chunkP,
    float* __restrict__ chunkH)
{
    int idx = blockIdx.x * 256 + threadIdx.x;
    float h = 0.f;
    for (int c = 0; c < NCHUNK; ++c) {
        size_t o = (size_t)c * 32768 + idx;
        float Pv = chunkP[o];
        float Hv = chunkH[o];
        chunkH[o] = h;
        h = fmaf(Pv, h, Hv);
    }
}

__global__ __launch_bounds__(256) void scanC_kernel(
    const unsigned short* __restrict__ dt,
    const unsigned short* __restrict__ xc,
    const unsigned short* __restrict__ z,
    const float* __restrict__ dbl,
    const float* __restrict__ Alog,
    const float* __restrict__ Dp,
    const float* __restrict__ chunkH,
    unsigned short* __restrict__ y,     // (B,L,1024) bf16, col offset dir*512
    int dir)
{
    __shared__ float B_s[CLEN][16];
    __shared__ float C_s[CLEN][16];
    int tid = threadIdx.x;
    int d = blockIdx.x * 256 + tid;
    int c = blockIdx.y;
    int b = blockIdx.z;
    int t0 = c * CLEN;
    size_t baserow = (size_t)b * LSEQ + t0;
    #pragma unroll
    for (int r = 0; r < 4; ++r) {
        int idx = tid + r * 256;
        int i = idx >> 4, n = idx & 15;
        B_s[i][n] = dbl[(baserow + i) * NDBL + 16 + n];
        C_s[i][n] = dbl[(baserow + i) * NDBL + 32 + n];
    }
    __syncthreads();
    float A[16];
    #pragma unroll
    for (int q = 0; q < 4; ++q) {
        f32x4 al = *reinterpret_cast<const f32x4*>(Alog + d * 16 + q * 4);
        #pragma unroll
        for (int j = 0; j < 4; ++j) A[q * 4 + j] = -__expf(al[j]);
    }
    float Dv = Dp[d];
    float h[16];
    size_t o = (((size_t)c * 4 + b) * 512 + d) * 16;
    #pragma unroll
    for (int q = 0; q < 4; ++q) {
        f32x4 hv = *reinterpret_cast<const f32x4*>(chunkH + o + q * 4);
        #pragma unroll
        for (int j = 0; j < 4; ++j) h[q * 4 + j] = hv[j];
    }
    int coloff = dir * 512;
    #pragma unroll 2
    for (int i = 0; i < CLEN; ++i) {
        size_t row = baserow + i;
        float sdt = bf2f(dt[row * 512 + d]);
        float sx  = bf2f(xc[row * 512 + d]);
        float zv  = bf2f(z [row * 512 + d]);
        float u = sdt * sx;
        float yacc = 0.f;
        #pragma unroll
        for (int n = 0; n < 16; ++n) {
            float dA = __expf(sdt * A[n]);
            h[n] = fmaf(dA, h[n], u * B_s[i][n]);
            yacc = fmaf(h[n], C_s[i][n], yacc);
        }
        int tout = dir ? (4095 - (t0 + i)) : (t0 + i);
        y[((size_t)b * LSEQ + tout) * 1024 + coloff + d] =
            f2bf((yacc + sx * Dv) * silu_f(zv));
    }
}

// ---------------------------------------------------------------------------
// out(B,C,L) = x + transpose(gout(B,L,C))
// ---------------------------------------------------------------------------
__global__ __launch_bounds__(256) void trans_out_kernel(
    const float* __restrict__ gout, const float* __restrict__ x,
    float* __restrict__ out)
{
    __shared__ float t[64][65];
    int tid = threadIdx.x;
    int m0 = blockIdx.x * 64;
    int c0 = blockIdx.y * 64;
    int b = m0 >> 12;
    int l0 = m0 & 4095;
    #pragma unroll
    for (int r = 0; r < 16; ++r) {
        int flat = tid + r * 256;
        int li = flat >> 6, ci = flat & 63;
        t[li][ci] = gout[(size_t)(m0 + li) * 256 + c0 + ci];
    }
    __syncthreads();
    #pragma unroll
    for (int r = 0; r < 16; ++r) {
        int flat = tid + r * 256;
        int ci = flat >> 6, li = flat & 63;
        size_t o = ((size_t)b * 256 + c0 + ci) * 4096 + l0 + li;
        out[o] = x[o] + t[li][ci];
    }
}

// ---------------------------------------------------------------------------
extern "C" void kernel_launch(void* const* d_in, const int* in_sizes, int n_in,
                              void* d_out, int out_size, void* d_ws, size_t ws_size,
                              hipStream_t stream) {
    const float* x        = (const float*)d_in[0];
    const float* time_emb = (const float*)d_in[1];
    const float* ln_g     = (const float*)d_in[2];
    const float* ln_b     = (const float*)d_in[3];
    const float* ada_w    = (const float*)d_in[4];
    const float* ada_b    = (const float*)d_in[5];
    const float* proj_w   = (const float*)d_in[6];
    const float* proj_b   = (const float*)d_in[7];

    float* ws = (float*)d_ws;
    float*          style     = ws;                                  // 4096 f
    unsigned short* xnorm_bf  = (unsigned short*)(ws + 4096);        // 16384x256
    unsigned short* xid_bf    = (unsigned short*)(ws + 2101248);     // 16384x512 (xi -> dt)
    unsigned short* z_bf      = (unsigned short*)(ws + 6295552);     // 16384x512
    unsigned short* xc_bf     = (unsigned short*)(ws + 10489856);    // 16384x512
    unsigned short* y_bf      = (unsigned short*)(ws + 14684160);    // 16384x1024
    float*          dbl       = ws + 23072768;                       // 16384x48
    float*          chunkP    = ws + 23859200;                       // 2097152
    float*          chunkH    = ws + 25956352;                       // 2097152
    unsigned short* outsum_bf = (unsigned short*)(ws + 28053504);    // 16384x256
    unsigned short* wbuf      = (unsigned short*)(ws + 30150656);
    unsigned short* inW_bf[2]    = { wbuf,           wbuf + 262144 };
    unsigned short* xprojW_bf[2] = { wbuf + 524288,  wbuf + 589824 };
    unsigned short* Wcat_bf      = wbuf + 655360;    // 256x1024
    unsigned short* projw_bf     = wbuf + 917504;    // 256x256
    float* gout = (float*)z_bf;   // 16384x256 f32, reuses z (dead by then)
    float* outp = (float*)d_out;

    style_kernel<<<8, 256, 0, stream>>>(time_emb, ada_w, ada_b, style);
    ln_kernel<<<BATCH * 256, 256, 0, stream>>>(x, ln_g, ln_b, style, xnorm_bf);

    // weight conversion
    for (int dir = 0; dir < 2; ++dir) {
        cvt_kernel<<<1024, 256, 0, stream>>>(
            (const float*)d_in[8 + dir * 9], inW_bf[dir], 262144);
        cvt_pad48_kernel<<<256, 256, 0, stream>>>(
            (const float*)d_in[11 + dir * 9], xprojW_bf[dir]);
    }
    cvt_cat_kernel<<<1024, 256, 0, stream>>>(
        (const float*)d_in[16], (const float*)d_in[25], Wcat_bf);
    cvt_kernel<<<256, 256, 0, stream>>>(proj_w, projw_bf, 65536);

    for (int dir = 0; dir < 2; ++dir) {
        const float* convW = (const float*)d_in[9 + dir * 9];
        const float* convB = (const float*)d_in[10 + dir * 9];
        const float* dtW   = (const float*)d_in[12 + dir * 9];
        const float* dtB   = (const float*)d_in[13 + dir * 9];
        const float* Alog  = (const float*)d_in[14 + dir * 9];
        const float* Dp    = (const float*)d_in[15 + dir * 9];

        mfma_gemm<0><<<dim3(8, 128), 256, 0, stream>>>(
            xnorm_bf, inW_bf[dir], xid_bf, z_bf, nullptr, 256, dir);
        conv_kernel<<<8192, 256, 0, stream>>>(xid_bf, convW, convB, xc_bf);
        mfma_gemm<1><<<dim3(1, 128), 256, 0, stream>>>(
            xc_bf, xprojW_bf[dir], dbl, nullptr, nullptr, 512, 0);
        dt_kernel<<<16384, 512, 0, stream>>>(dbl, dtW, dtB, xid_bf);
        scanA_kernel<<<dim3(2, NCHUNK, BATCH), 256, 0, stream>>>(
            xid_bf, xc_bf, dbl, Alog, chunkP, chunkH);
        scanB_kernel<<<128, 256, 0, stream>>>(chunkP, chunkH);
        scanC_kernel<<<dim3(2, NCHUNK, BATCH), 256, 0, stream>>>(
            xid_bf, xc_bf, z_bf, dbl, Alog, Dp, chunkH, y_bf, dir);
    }

    mfma_gemm<2><<<dim3(2, 128), 256, 0, stream>>>(
        y_bf, Wcat_bf, outsum_bf, nullptr, nullptr, 1024, 0);
    mfma_gemm<3><<<dim3(2, 128), 256, 0, stream>>>(
        outsum_bf, projw_bf, gout, nullptr, proj_b, 256, 0);
    trans_out_kernel<<<dim3(256, 4), 256, 0, stream>>>(gout, x, outp);
}